// Round 11
// baseline (52.522 us; speedup 1.0000x reference)
//
#include <hip/hip_runtime.h>
#include <math.h>

#define MLEN 4096
#define LOG2M 12
#define RANK 8
#define NSAMP 2048
#define VEC 8      // m-points per thread (strided by 256)
#define NS  4      // samples (n) per thread, reusing Hft loads

__device__ __forceinline__ float softplus_f(float x) {
    return (x > 20.0f) ? x : log1pf(expf(x));
}

// ---------------------------------------------------------------------------
// MEASUREMENT ROUND: this file is the round-6 source (33.1 us total) with ONE
// change: fft_rows_kernel is launched 3x (idempotent). dur_us = 3*fft + mix,
// and round-7's bench gave fft + mix = 33.1 -> fft = (dur_new - 33.1) / 2.
// ---------------------------------------------------------------------------

// Kernel 1: full complex FFT of softplus(H) rows -> Hft in d_ws (256 KB).
// In-place iterative DIT (bit-reversed load), 32 KB LDS, 1024 threads/block.
// One block per row (8 blocks). Pure __sinf/__cosf twiddles.
__global__ __launch_bounds__(1024) void fft_rows_kernel(const float* __restrict__ H,
                                                        float2* __restrict__ Hft) {
    __shared__ float2 buf[MLEN];            // 32 KB
    const int d = blockIdx.x;
    const float* row = H + d * MLEN;

    for (int i = threadIdx.x; i < MLEN; i += 1024) {
        int src = (int)(__brev((unsigned)i) >> (32 - LOG2M));
        buf[i] = make_float2(softplus_f(row[src]), 0.0f);
    }
    __syncthreads();

    for (int s = 1; s <= LOG2M; ++s) {
        const int half = 1 << (s - 1);
#pragma unroll 2
        for (int p = threadIdx.x; p < (MLEN >> 1); p += 1024) {
            const int k  = p & (half - 1);
            const int i0 = ((p >> (s - 1)) << s) + k;
            const int i1 = i0 + half;
            const float ang = -6.28318530717958647692f * (float)k / (float)(half << 1);
            const float sw = __sinf(ang);
            const float cw = __cosf(ang);
            float2 a = buf[i0];
            float2 b = buf[i1];
            float tr = b.x * cw - b.y * sw;
            float ti = b.x * sw + b.y * cw;
            buf[i0] = make_float2(a.x + tr, a.y + ti);
            buf[i1] = make_float2(a.x - tr, a.y - ti);
        }
        __syncthreads();
    }

    float2* outrow = Hft + d * MLEN;
    for (int i = threadIdx.x; i < MLEN; i += 1024) outrow[i] = buf[i];
}

// Kernel 2: V[n,m] = sum_d softplus(W[n,d]) * exp(-i*2pi*tau[n,d]*m/M) * Hft[d,m]
// EXACT round-6 mix (best measured total): phase recurrence, per-thread
// native sin/cos for base+step phasors, NS=4 x VEC=8, no unroll pragmas on d,
// no forced occupancy bound.
template <int REAL_ONLY>
__global__ __launch_bounds__(256) void mix_kernel(const float* __restrict__ W,
                                                  const float* __restrict__ tau,
                                                  const float2* __restrict__ Hft,
                                                  float* __restrict__ out) {
    const int tid = threadIdx.x;
    const int m0  = blockIdx.x * (256 * VEC) + tid;
    const int n0  = blockIdx.y * NS;

    __shared__ float s_spw[NS * RANK];
    __shared__ float s_tau[NS * RANK];
    if (tid < NS * RANK) {
        s_spw[tid] = softplus_f(W[n0 * RANK + tid]);
        s_tau[tid] = tau[n0 * RANK + tid];
    }
    __syncthreads();

    float ar[NS][VEC];
    float ai[NS][VEC];   // dead (DCE) in REAL_ONLY instantiation
#pragma unroll
    for (int j = 0; j < NS; ++j)
#pragma unroll
        for (int k = 0; k < VEC; ++k) { ar[j][k] = 0.0f; ai[j][k] = 0.0f; }

    const float th0f = -6.28318530717958647692f * ((float)m0 * (1.0f / (float)MLEN));
    const float dthf = -6.28318530717958647692f * (256.0f / (float)MLEN);

#pragma unroll
    for (int d = 0; d < RANK; ++d) {
        float cs[NS], sn[NS], dc[NS], ds[NS];
#pragma unroll
        for (int j = 0; j < NS; ++j) {
            const float t   = s_tau[j * RANK + d];
            const float spw = s_spw[j * RANK + d];
            const float a0 = th0f * t;
            const float a1 = dthf * t;
            const float c0 = __cosf(a0);
            const float s0 = __sinf(a0);
            dc[j] = __cosf(a1);
            ds[j] = __sinf(a1);
            cs[j] = spw * c0;             // phasor pre-scaled by softplus(W)
            sn[j] = spw * s0;
        }
        const float2* __restrict__ hrow = Hft + d * MLEN + m0;
        float2 hv[VEC];
#pragma unroll
        for (int k = 0; k < VEC; ++k) hv[k] = hrow[k * 256];
#pragma unroll
        for (int k = 0; k < VEC; ++k) {
#pragma unroll
            for (int j = 0; j < NS; ++j) {
                ar[j][k] += cs[j] * hv[k].x - sn[j] * hv[k].y;
                if (!REAL_ONLY) ai[j][k] += cs[j] * hv[k].y + sn[j] * hv[k].x;
                const float ncs = cs[j] * dc[j] - sn[j] * ds[j];
                sn[j] = cs[j] * ds[j] + sn[j] * dc[j];
                cs[j] = ncs;
            }
        }
    }

#pragma unroll
    for (int j = 0; j < NS; ++j) {
#pragma unroll
        for (int k = 0; k < VEC; ++k) {
            const size_t idx = (size_t)(n0 + j) * MLEN + m0 + k * 256;
            if (REAL_ONLY) out[idx] = ar[j][k];
            else ((float2*)out)[idx] = make_float2(ar[j][k], ai[j][k]);
        }
    }
}

extern "C" void kernel_launch(void* const* d_in, const int* in_sizes, int n_in,
                              void* d_out, int out_size, void* d_ws, size_t ws_size,
                              hipStream_t stream) {
    const float* W   = (const float*)d_in[0];   // (N, R)
    const float* H   = (const float*)d_in[1];   // (R, M)
    const float* tau = (const float*)d_in[2];   // (N, R)
    float2* Hft = (float2*)d_ws;                // (R, M) complex, 256 KB scratch
    float* out  = (float*)d_out;

    // 3 identical (idempotent) fft launches: dur_us = 3*fft + mix.
    fft_rows_kernel<<<RANK, 1024, 0, stream>>>(H, Hft);
    fft_rows_kernel<<<RANK, 1024, 0, stream>>>(H, Hft);
    fft_rows_kernel<<<RANK, 1024, 0, stream>>>(H, Hft);

    const long long NM = (long long)NSAMP * MLEN;
    dim3 grid(MLEN / (256 * VEC), NSAMP / NS);
    if ((long long)out_size >= 2 * NM) {
        mix_kernel<0><<<grid, 256, 0, stream>>>(W, tau, Hft, out);
    } else {
        mix_kernel<1><<<grid, 256, 0, stream>>>(W, tau, Hft, out);
    }
}

// Round 12
// 33.497 us; speedup vs baseline: 1.5679x; 1.5679x over previous
//
#include <hip/hip_runtime.h>
#include <math.h>

#define MLEN 4096
#define RANK 8
#define NSAMP 2048
#define VEC 8      // consecutive m-points per thread
#define NS  4      // samples (n) per thread, reusing Hft loads

__device__ __forceinline__ float softplus_f(float x) {
    return (x > 20.0f) ? x : log1pf(expf(x));
}

__device__ __forceinline__ float2 cmulf(float2 a, float2 b) {
    return make_float2(a.x * b.x - a.y * b.y, a.x * b.y + a.y * b.x);
}

// ---------------------------------------------------------------------------
// Wave-level 64-point FFT: radix-2 DIF across lanes via shfl_xor.
// Input natural order (lane l = index l); output: lane l holds X[bitrev6(l)].
// 6 stages x (2 shfl + ~12 VALU + 1 native sincos pair). No LDS, no barriers.
// ---------------------------------------------------------------------------
__device__ __forceinline__ float2 wave_fft64(float2 v, int l) {
#pragma unroll
    for (int h = 32; h >= 1; h >>= 1) {
        const float tx = __shfl_xor(v.x, h);
        const float ty = __shfl_xor(v.y, h);
        const bool hi = (l & h) != 0;
        const float s = hi ? -1.0f : 1.0f;
        // lo: v+t ; hi: t-v   (u = t + s*(-? ) -> t + s*v with s=-1 gives t-v)
        float2 u = make_float2(fmaf(s, v.x, tx), fmaf(s, v.y, ty));
        const int idx = hi ? (l & (h - 1)) : 0;
        const float ang = -3.14159265358979323846f * (float)idx / (float)h;
        const float cw = __cosf(ang), sw = __sinf(ang);
        v = make_float2(u.x * cw - u.y * sw, u.x * sw + u.y * cw);
    }
    return v;
}

// ---------------------------------------------------------------------------
// Four-step FFT (4096 = 64 x 64), per row d of softplus(H):
//   n = 64*n1 + n2, k = k1 + 64*k2
//   A: Y[k1,n2] = FFT64_{n1}(x[64*n1+n2]);  Z[k1,n2] = Y * W4096^{n2*k1}
//   B: X[k1+64*k2] = FFT64_{n2}(Z[k1,n2])
// 512 independent waves per step -> 128 blocks of 256 (vs 8 blocks before).
// ---------------------------------------------------------------------------
__global__ __launch_bounds__(256) void fftA_kernel(const float* __restrict__ H,
                                                   float2* __restrict__ Z) {
    const int wid = (blockIdx.x << 2) + (threadIdx.x >> 6);  // 0..511
    const int l   = threadIdx.x & 63;                        // = n1
    const int d   = wid >> 6;
    const int n2  = wid & 63;

    const float x = softplus_f(H[d * MLEN + (l << 6) + n2]);
    float2 v = wave_fft64(make_float2(x, 0.0f), l);
    const int k1 = (int)(__brev((unsigned)l) >> 26);         // output index
    const float ang = -3.14159265358979323846f / 2048.0f * (float)(n2 * k1);
    v = cmulf(v, make_float2(__cosf(ang), __sinf(ang)));
    Z[d * MLEN + (k1 << 6) + n2] = v;                        // scattered 8B (256 KB total)
}

__global__ __launch_bounds__(256) void fftB_kernel(const float2* __restrict__ Z,
                                                   float2* __restrict__ Hft) {
    const int wid = (blockIdx.x << 2) + (threadIdx.x >> 6);  // 0..511
    const int l   = threadIdx.x & 63;                        // = n2
    const int d   = wid >> 6;
    const int k1  = wid & 63;

    float2 v = Z[d * MLEN + (k1 << 6) + l];                  // coalesced
    v = wave_fft64(v, l);
    const int k2 = (int)(__brev((unsigned)l) >> 26);
    Hft[d * MLEN + (k2 << 6) + k1] = v;                      // scattered 8B
}

// ---------------------------------------------------------------------------
// Mix: V[n,m] = sum_d softplus(W[n,d]) * exp(-i*2pi*tau[n,d]*m/M) * Hft[d,m]
// Consecutive-m layout: thread owns m0..m0+7 -> float4 loads/stores, and the
// step phasor exp(-i*2pi*tau/M) is thread-uniform (from LDS). Register
// double-buffer (hvA/hvB named scalars) pipelines rank d+1's loads under
// rank d's ~460-cycle compute. Outer d-loop unroll 1 (anti-hoist, R8 lesson).
// ---------------------------------------------------------------------------
template <int REAL_ONLY>
__device__ __forceinline__ void accum_rank(int d,
    const float4& h0, const float4& h1, const float4& h2, const float4& h3,
    const float* s_spw, const float* s_tau, const float2* s_step,
    float thm, float (&ar)[NS][VEC], float (&ai)[NS][VEC]) {
    float cs[NS], sn[NS], dc[NS], ds[NS];
#pragma unroll
    for (int j = 0; j < NS; ++j) {
        const float t   = s_tau[j * RANK + d];
        const float spw = s_spw[j * RANK + d];
        const float a0  = thm * t;
        cs[j] = spw * __cosf(a0);          // phasor pre-scaled by softplus(W)
        sn[j] = spw * __sinf(a0);
        const float2 st = s_step[j * RANK + d];
        dc[j] = st.x; ds[j] = st.y;
    }
#pragma unroll
    for (int k = 0; k < VEC; ++k) {
        const float4& hq = (k < 2) ? h0 : (k < 4) ? h1 : (k < 6) ? h2 : h3;
        const float hx = (k & 1) ? hq.z : hq.x;
        const float hy = (k & 1) ? hq.w : hq.y;
#pragma unroll
        for (int j = 0; j < NS; ++j) {
            ar[j][k] += cs[j] * hx - sn[j] * hy;
            if (!REAL_ONLY) ai[j][k] += cs[j] * hy + sn[j] * hx;
            if (k < VEC - 1) {
                const float ncs = cs[j] * dc[j] - sn[j] * ds[j];
                sn[j] = cs[j] * ds[j] + sn[j] * dc[j];
                cs[j] = ncs;
            }
        }
    }
}

template <int REAL_ONLY>
__global__ __launch_bounds__(256) void mix_kernel(const float* __restrict__ W,
                                                  const float* __restrict__ tau,
                                                  const float2* __restrict__ Hft,
                                                  float* __restrict__ out) {
    const int tid = threadIdx.x;
    const int m0  = (blockIdx.x * 256 + tid) * VEC;   // consecutive 8 m's
    const int n0  = blockIdx.y * NS;

    __shared__ float  s_spw[NS * RANK];
    __shared__ float  s_tau[NS * RANK];
    __shared__ float2 s_step[NS * RANK];    // exp(-i*2pi*tau/M): thread-uniform step
    if (tid < NS * RANK) {
        const float t = tau[n0 * RANK + tid];
        s_spw[tid] = softplus_f(W[n0 * RANK + tid]);
        s_tau[tid] = t;
        const float a1 = -1.53398078788564122971e-3f * t;   // -2*pi/4096 * t
        s_step[tid] = make_float2(__cosf(a1), __sinf(a1));
    }
    __syncthreads();

    float ar[NS][VEC];
    float ai[NS][VEC];   // dead (DCE) in REAL_ONLY instantiation
#pragma unroll
    for (int j = 0; j < NS; ++j)
#pragma unroll
        for (int k = 0; k < VEC; ++k) { ar[j][k] = 0.0f; ai[j][k] = 0.0f; }

    const float thm = -6.28318530717958647692f * ((float)m0 * (1.0f / (float)MLEN));

    // preload rank 0
    const float4* p0 = reinterpret_cast<const float4*>(Hft + m0);
    float4 hA0 = p0[0], hA1 = p0[1], hA2 = p0[2], hA3 = p0[3];

#pragma unroll 1
    for (int d = 0; d < RANK; d += 2) {
        const float4* pB = reinterpret_cast<const float4*>(Hft + (d + 1) * MLEN + m0);
        float4 hB0 = pB[0], hB1 = pB[1], hB2 = pB[2], hB3 = pB[3];
        accum_rank<REAL_ONLY>(d, hA0, hA1, hA2, hA3, s_spw, s_tau, s_step, thm, ar, ai);
        if (d + 2 < RANK) {
            const float4* pA = reinterpret_cast<const float4*>(Hft + (d + 2) * MLEN + m0);
            hA0 = pA[0]; hA1 = pA[1]; hA2 = pA[2]; hA3 = pA[3];
        }
        accum_rank<REAL_ONLY>(d + 1, hB0, hB1, hB2, hB3, s_spw, s_tau, s_step, thm, ar, ai);
    }

#pragma unroll
    for (int j = 0; j < NS; ++j) {
        if (REAL_ONLY) {
            float* po = out + (size_t)(n0 + j) * MLEN + m0;
            float4 o0 = make_float4(ar[j][0], ar[j][1], ar[j][2], ar[j][3]);
            float4 o1 = make_float4(ar[j][4], ar[j][5], ar[j][6], ar[j][7]);
            reinterpret_cast<float4*>(po)[0] = o0;
            reinterpret_cast<float4*>(po)[1] = o1;
        } else {
            float2* po = (float2*)out + (size_t)(n0 + j) * MLEN + m0;
#pragma unroll
            for (int q = 0; q < 4; ++q) {
                float4 o = make_float4(ar[j][2 * q], ai[j][2 * q],
                                       ar[j][2 * q + 1], ai[j][2 * q + 1]);
                reinterpret_cast<float4*>(po)[q] = o;
            }
        }
    }
}

extern "C" void kernel_launch(void* const* d_in, const int* in_sizes, int n_in,
                              void* d_out, int out_size, void* d_ws, size_t ws_size,
                              hipStream_t stream) {
    const float* W   = (const float*)d_in[0];   // (N, R)
    const float* H   = (const float*)d_in[1];   // (R, M)
    const float* tau = (const float*)d_in[2];   // (N, R)
    float2* Z   = (float2*)d_ws;                // (R, M) complex, 256 KB
    float2* Hft = Z + RANK * MLEN;              // (R, M) complex, 256 KB
    float* out  = (float*)d_out;

    fftA_kernel<<<128, 256, 0, stream>>>(H, Z);
    fftB_kernel<<<128, 256, 0, stream>>>(Z, Hft);

    const long long NM = (long long)NSAMP * MLEN;
    dim3 grid(MLEN / (256 * VEC), NSAMP / NS);
    if ((long long)out_size >= 2 * NM) {
        mix_kernel<0><<<grid, 256, 0, stream>>>(W, tau, Hft, out);
    } else {
        mix_kernel<1><<<grid, 256, 0, stream>>>(W, tau, Hft, out);
    }
}